// Round 1
// baseline (619.080 us; speedup 1.0000x reference)
//
#include <hip/hip_runtime.h>

constexpr int HID = 64;

// ---- degree: deg[v] = #edges with dst==v (self-loop +1 added in k_dinv) ----
__global__ __launch_bounds__(256) void k_deg(const int* __restrict__ dst, int nE,
                                             float* __restrict__ deg) {
  int i = blockIdx.x * 256 + threadIdx.x;
  if (i < nE) atomicAdd(&deg[dst[i]], 1.0f);
}

__global__ __launch_bounds__(256) void k_dinv(float* __restrict__ deg, int nN) {
  int i = blockIdx.x * 256 + threadIdx.x;
  if (i < nN) deg[i] = rsqrtf(deg[i] + 1.0f);   // +1 = self-loop
}

// ---- fused matmul + row scale: out[v,c] = dinv[v] * sum_k X[v,k]*W[k,c] ----
// one wave per row (lane = output channel), 16 rows per 256-thread block
template <int K>
__global__ __launch_bounds__(256) void k_mm_scale(const float* __restrict__ X,
                                                  const float* __restrict__ W,
                                                  const float* __restrict__ dinv,
                                                  float* __restrict__ out, int nRows) {
  __shared__ float Ws[K * HID];
  for (int t = threadIdx.x; t < K * HID; t += 256) Ws[t] = W[t];
  __syncthreads();
  const int lane = threadIdx.x & 63;
  const int wid  = threadIdx.x >> 6;
  const int base = blockIdx.x * 16;
  for (int i = 0; i < 4; ++i) {
    int row = base + i * 4 + wid;
    if (row < nRows) {
      const float* xr = X + (size_t)row * K;
      float acc = 0.f;
#pragma unroll 8
      for (int k = 0; k < K; ++k) acc = fmaf(xr[k], Ws[k * HID + lane], acc);
      out[(size_t)row * HID + lane] = acc * dinv[row];
    }
  }
}

// ---- edge scatter: acc[dst] += h_s[src], one wave per edge, lane = channel ----
__global__ __launch_bounds__(256) void k_scatter(const int* __restrict__ src,
                                                 const int* __restrict__ dst, int nE,
                                                 const float* __restrict__ H,
                                                 float* __restrict__ acc) {
  int gid  = blockIdx.x * 256 + threadIdx.x;
  int e    = gid >> 6;
  int lane = gid & 63;
  if (e < nE) {
    int s = src[e], d = dst[e];
    atomicAdd(&acc[(size_t)d * HID + lane], H[(size_t)s * HID + lane]);
  }
}

// ---- epilogue layer1: z[v,c] = relu(dinv[v]*(acc+h_s) + b[c]) in place over h_s ----
__global__ __launch_bounds__(256) void k_post(const float* __restrict__ acc,
                                              float* __restrict__ hs,
                                              const float* __restrict__ dinv,
                                              const float* __restrict__ b, int nN) {
  int idx = blockIdx.x * 256 + threadIdx.x;
  int v = idx >> 6, c = idx & 63;
  if (v < nN) {
    hs[idx] = fmaxf(fmaf(dinv[v], acc[idx] + hs[idx], b[c]), 0.f);
  }
}

// ---- epilogue layer2 fused with pooling scatter ----
__global__ __launch_bounds__(256) void k_post_pool(const float* __restrict__ acc,
                                                   const float* __restrict__ hs,
                                                   const float* __restrict__ dinv,
                                                   const float* __restrict__ b,
                                                   const int* __restrict__ batch,
                                                   float* __restrict__ gsum,
                                                   float* __restrict__ gcnt, int nN) {
  int idx = blockIdx.x * 256 + threadIdx.x;
  int v = idx >> 6, c = idx & 63;
  if (v < nN) {
    float h = fmaxf(fmaf(dinv[v], acc[idx] + hs[idx], b[c]), 0.f);
    int g = batch[v];
    atomicAdd(&gsum[(size_t)g * HID + c], h);
    if (c == 0) atomicAdd(&gcnt[g], 1.0f);
  }
}

// ---- head: out[g,:] = (gsum[g]/max(cnt,1)) @ Wl + bl, one wave per graph ----
__global__ __launch_bounds__(256) void k_head(const float* __restrict__ gsum,
                                              const float* __restrict__ gcnt,
                                              const float* __restrict__ Wl,
                                              const float* __restrict__ bl,
                                              float* __restrict__ out, int nG) {
  int gid = blockIdx.x * 256 + threadIdx.x;
  int g = gid >> 6, lane = gid & 63;
  if (g >= nG) return;
  float val = gsum[(size_t)g * HID + lane] / fmaxf(gcnt[g], 1.0f);
  float p0 = val * Wl[lane * 2 + 0];
  float p1 = val * Wl[lane * 2 + 1];
#pragma unroll
  for (int off = 32; off; off >>= 1) {
    p0 += __shfl_xor(p0, off, 64);
    p1 += __shfl_xor(p1, off, 64);
  }
  if (lane == 0) {
    out[g * 2 + 0] = p0 + bl[0];
    out[g * 2 + 1] = p1 + bl[1];
  }
}

extern "C" void kernel_launch(void* const* d_in, const int* in_sizes, int n_in,
                              void* d_out, int out_size, void* d_ws, size_t ws_size,
                              hipStream_t stream) {
  const float* x     = (const float*)d_in[0];
  const int*   ei    = (const int*)d_in[1];
  const int*   batch = (const int*)d_in[2];
  const float* W1    = (const float*)d_in[3];
  const float* b1    = (const float*)d_in[4];
  const float* W2    = (const float*)d_in[5];
  const float* b2    = (const float*)d_in[6];
  const float* Wl    = (const float*)d_in[7];
  const float* bl    = (const float*)d_in[8];
  float* out = (float*)d_out;

  const int nN = in_sizes[2];          // 50000
  const int nE = in_sizes[1] / 2;      // 800000
  const int nG = out_size / 2;         // 512
  const int* src = ei;
  const int* dst = ei + nE;

  char* ws = (char*)d_ws;
  size_t off = 0;
  auto alloc = [&](size_t bytes) {
    char* p = ws + off;
    off += (bytes + 255) & ~(size_t)255;
    return p;
  };
  float* dinv = (float*)alloc((size_t)nN * 4);
  float* A    = (float*)alloc((size_t)nN * HID * 4);   // h_s / z1
  float* B    = (float*)alloc((size_t)nN * HID * 4);   // acc1 / h_s2
  float* gsum = (float*)alloc((size_t)nG * HID * 4);
  float* gcnt = (float*)alloc((size_t)nG * 4);

  // degree -> dinv
  hipMemsetAsync(dinv, 0, (size_t)nN * 4, stream);
  k_deg<<<(nE + 255) / 256, 256, 0, stream>>>(dst, nE, dinv);
  k_dinv<<<(nN + 255) / 256, 256, 0, stream>>>(dinv, nN);

  // layer 1
  k_mm_scale<128><<<(nN + 15) / 16, 256, 0, stream>>>(x, W1, dinv, A, nN);
  hipMemsetAsync(B, 0, (size_t)nN * HID * 4, stream);
  k_scatter<<<(int)(((size_t)nE * 64 + 255) / 256), 256, 0, stream>>>(src, dst, nE, A, B);
  k_post<<<(nN * HID + 255) / 256, 256, 0, stream>>>(B, A, dinv, b1, nN);

  // layer 2
  k_mm_scale<64><<<(nN + 15) / 16, 256, 0, stream>>>(A, W2, dinv, B, nN);
  hipMemsetAsync(A, 0, (size_t)nN * HID * 4, stream);
  k_scatter<<<(int)(((size_t)nE * 64 + 255) / 256), 256, 0, stream>>>(src, dst, nE, B, A);

  // pooling
  hipMemsetAsync(gsum, 0, (size_t)nG * HID * 4, stream);
  hipMemsetAsync(gcnt, 0, (size_t)nG * 4, stream);
  k_post_pool<<<(nN * HID + 255) / 256, 256, 0, stream>>>(A, B, dinv, b2, batch, gsum, gcnt, nN);

  // head
  k_head<<<(nG * 64 + 255) / 256, 256, 0, stream>>>(gsum, gcnt, Wl, bl, out, nG);
}

// Round 2
// 305.715 us; speedup vs baseline: 2.0250x; 2.0250x over previous
//
#include <hip/hip_runtime.h>

constexpr int HID = 64;
constexpr int SCAN_NB = 256;   // max blocks for hierarchical scan (196 used)

// ---- int histogram of dst ----
__global__ __launch_bounds__(256) void k_hist(const int* __restrict__ dst, int nE,
                                              int* __restrict__ deg) {
  int i = blockIdx.x * 256 + threadIdx.x;
  if (i < nE) atomicAdd(&deg[dst[i]], 1);
}

__global__ __launch_bounds__(256) void k_dinv(const int* __restrict__ deg,
                                              float* __restrict__ dinv, int nN) {
  int i = blockIdx.x * 256 + threadIdx.x;
  if (i < nN) dinv[i] = rsqrtf((float)deg[i] + 1.0f);   // +1 = self-loop
}

// ---- hierarchical exclusive scan of deg -> row_start (and cursor copy) ----
__global__ __launch_bounds__(256) void k_scanA(const int* __restrict__ deg, int nN,
                                               int* __restrict__ partial) {
  __shared__ int s[256];
  int v = blockIdx.x * 256 + threadIdx.x;
  s[threadIdx.x] = (v < nN) ? deg[v] : 0;
  __syncthreads();
  for (int d = 128; d; d >>= 1) {
    if (threadIdx.x < d) s[threadIdx.x] += s[threadIdx.x + d];
    __syncthreads();
  }
  if (threadIdx.x == 0) partial[blockIdx.x] = s[0];
}

__global__ __launch_bounds__(256) void k_scanB(int* __restrict__ partial, int nB,
                                               int* __restrict__ partial_ex,
                                               int* __restrict__ row_start, int nN) {
  __shared__ int s[256];
  int t = threadIdx.x;
  int own = (t < nB) ? partial[t] : 0;
  s[t] = own;
  __syncthreads();
  for (int d = 1; d < 256; d <<= 1) {
    int x = s[t];
    if (t >= d) x += s[t - d];
    __syncthreads();
    s[t] = x;
    __syncthreads();
  }
  partial_ex[t] = s[t] - own;          // exclusive
  if (t == 255) row_start[nN] = s[255]; // total = nE
}

__global__ __launch_bounds__(256) void k_scanC(const int* __restrict__ deg, int nN,
                                               const int* __restrict__ partial_ex,
                                               int* __restrict__ row_start,
                                               int* __restrict__ cursor) {
  __shared__ int s[256];
  int t = threadIdx.x;
  int v = blockIdx.x * 256 + t;
  int own = (v < nN) ? deg[v] : 0;
  s[t] = own;
  __syncthreads();
  for (int d = 1; d < 256; d <<= 1) {
    int x = s[t];
    if (t >= d) x += s[t - d];
    __syncthreads();
    s[t] = x;
    __syncthreads();
  }
  if (v < nN) {
    int rs = partial_ex[blockIdx.x] + s[t] - own;
    row_start[v] = rs;
    cursor[v] = rs;
  }
}

// ---- CSR fill ----
__global__ __launch_bounds__(256) void k_fill(const int* __restrict__ src,
                                              const int* __restrict__ dst, int nE,
                                              int* __restrict__ cursor,
                                              int* __restrict__ csr) {
  int e = blockIdx.x * 256 + threadIdx.x;
  if (e < nE) {
    int pos = atomicAdd(&cursor[dst[e]], 1);
    csr[pos] = src[e];
  }
}

// ---- fused matmul + row scale: out[v,c] = dinv[v] * sum_k X[v,k]*W[k,c] ----
template <int K>
__global__ __launch_bounds__(256) void k_mm_scale(const float* __restrict__ X,
                                                  const float* __restrict__ W,
                                                  const float* __restrict__ dinv,
                                                  float* __restrict__ out, int nRows) {
  __shared__ float Ws[K * HID];
  for (int t = threadIdx.x; t < K * HID; t += 256) Ws[t] = W[t];
  __syncthreads();
  const int lane = threadIdx.x & 63;
  const int wid  = threadIdx.x >> 6;
  const int base = blockIdx.x * 16;
  for (int i = 0; i < 4; ++i) {
    int row = base + i * 4 + wid;
    if (row < nRows) {
      const float* xr = X + (size_t)row * K;
      float acc = 0.f;
#pragma unroll 8
      for (int k = 0; k < K; ++k) acc = fmaf(xr[k], Ws[k * HID + lane], acc);
      out[(size_t)row * HID + lane] = acc * dinv[row];
    }
  }
}

// ---- fused gather + self-loop + epilogue: one wave per node ----
// out[v,c] = relu(dinv[v]*(H[v,c] + sum_{e in CSR[v]} H[src_e,c]) + b[c])
__global__ __launch_bounds__(256) void k_gather_post(const int* __restrict__ csr,
                                                     const int* __restrict__ row_start,
                                                     const float* __restrict__ H,
                                                     const float* __restrict__ dinv,
                                                     const float* __restrict__ b,
                                                     float* __restrict__ out, int nN) {
  int wid = threadIdx.x >> 6;
  int lane = threadIdx.x & 63;
  int v = blockIdx.x * 4 + wid;
  if (v >= nN) return;
  int lo = row_start[v], hi = row_start[v + 1];
  float a0 = H[(size_t)v * HID + lane];   // self-loop
  float a1 = 0.f;
  for (int p = lo; p < hi; p += 64) {
    int n = min(64, hi - p);
    int idx = (p + lane < hi) ? csr[p + lane] : 0;
    int j = 0;
    for (; j + 1 < n; j += 2) {
      int s0 = __shfl(idx, j, 64);
      int s1 = __shfl(idx, j + 1, 64);
      a0 += H[(size_t)s0 * HID + lane];
      a1 += H[(size_t)s1 * HID + lane];
    }
    if (j < n) {
      int s0 = __shfl(idx, j, 64);
      a0 += H[(size_t)s0 * HID + lane];
    }
  }
  out[(size_t)v * HID + lane] = fmaxf(fmaf(dinv[v], a0 + a1, b[lane]), 0.f);
}

// ---- pooling + head, atomic-free (batch is sorted): one block per graph ----
__device__ inline int lowerb(const int* __restrict__ a, int n, int key) {
  int lo = 0, hi = n;
  while (lo < hi) {
    int mid = (lo + hi) >> 1;
    if (a[mid] < key) lo = mid + 1; else hi = mid;
  }
  return lo;
}

__global__ __launch_bounds__(256) void k_pool_head(const float* __restrict__ Z,
                                                   const int* __restrict__ batch, int nN,
                                                   const float* __restrict__ Wl,
                                                   const float* __restrict__ bl,
                                                   float* __restrict__ out) {
  int g = blockIdx.x;
  int lane = threadIdx.x & 63;
  int wid = threadIdx.x >> 6;
  int lo = lowerb(batch, nN, g);
  int hi = lowerb(batch, nN, g + 1);
  float acc = 0.f;
  for (int r = lo + wid; r < hi; r += 4) acc += Z[(size_t)r * HID + lane];
  __shared__ float s[4][HID];
  s[wid][lane] = acc;
  __syncthreads();
  if (wid == 0) {
    float tot = s[0][lane] + s[1][lane] + s[2][lane] + s[3][lane];
    float mean = tot / fmaxf((float)(hi - lo), 1.0f);
    float p0 = mean * Wl[lane * 2 + 0];
    float p1 = mean * Wl[lane * 2 + 1];
#pragma unroll
    for (int off = 32; off; off >>= 1) {
      p0 += __shfl_xor(p0, off, 64);
      p1 += __shfl_xor(p1, off, 64);
    }
    if (lane == 0) {
      out[g * 2 + 0] = p0 + bl[0];
      out[g * 2 + 1] = p1 + bl[1];
    }
  }
}

extern "C" void kernel_launch(void* const* d_in, const int* in_sizes, int n_in,
                              void* d_out, int out_size, void* d_ws, size_t ws_size,
                              hipStream_t stream) {
  const float* x     = (const float*)d_in[0];
  const int*   ei    = (const int*)d_in[1];
  const int*   batch = (const int*)d_in[2];
  const float* W1    = (const float*)d_in[3];
  const float* b1    = (const float*)d_in[4];
  const float* W2    = (const float*)d_in[5];
  const float* b2    = (const float*)d_in[6];
  const float* Wl    = (const float*)d_in[7];
  const float* bl    = (const float*)d_in[8];
  float* out = (float*)d_out;

  const int nN = in_sizes[2];          // 50000
  const int nE = in_sizes[1] / 2;      // 800000
  const int nG = out_size / 2;         // 512
  const int* src = ei;
  const int* dst = ei + nE;

  char* ws = (char*)d_ws;
  size_t off = 0;
  auto alloc = [&](size_t bytes) {
    char* p = ws + off;
    off += (bytes + 255) & ~(size_t)255;
    return p;
  };
  int*   deg       = (int*)alloc((size_t)nN * 4);
  int*   row_start = (int*)alloc(((size_t)nN + 1) * 4);
  int*   cursor    = (int*)alloc((size_t)nN * 4);
  int*   csr       = (int*)alloc((size_t)nE * 4);
  int*   partial   = (int*)alloc(SCAN_NB * 4);
  int*   partialex = (int*)alloc(SCAN_NB * 4);
  float* dinv      = (float*)alloc((size_t)nN * 4);
  float* A         = (float*)alloc((size_t)nN * HID * 4);
  float* B         = (float*)alloc((size_t)nN * HID * 4);

  const int nB = (nN + 255) / 256;     // 196 scan blocks

  // CSR build
  hipMemsetAsync(deg, 0, (size_t)nN * 4, stream);
  k_hist<<<(nE + 255) / 256, 256, 0, stream>>>(dst, nE, deg);
  k_dinv<<<nB, 256, 0, stream>>>(deg, dinv, nN);
  k_scanA<<<nB, 256, 0, stream>>>(deg, nN, partial);
  k_scanB<<<1, 256, 0, stream>>>(partial, nB, partialex, row_start, nN);
  k_scanC<<<nB, 256, 0, stream>>>(deg, nN, partialex, row_start, cursor);
  k_fill<<<(nE + 255) / 256, 256, 0, stream>>>(src, dst, nE, cursor, csr);

  // layer 1: H_s = dinv*(x@W1) ; z1 = relu(dinv*(gather+self)+b1)
  k_mm_scale<128><<<(nN + 15) / 16, 256, 0, stream>>>(x, W1, dinv, A, nN);
  k_gather_post<<<(nN + 3) / 4, 256, 0, stream>>>(csr, row_start, A, dinv, b1, B, nN);

  // layer 2
  k_mm_scale<64><<<(nN + 15) / 16, 256, 0, stream>>>(B, W2, dinv, A, nN);
  k_gather_post<<<(nN + 3) / 4, 256, 0, stream>>>(csr, row_start, A, dinv, b2, B, nN);

  // pooling + head
  k_pool_head<<<nG, 256, 0, stream>>>(B, batch, nN, Wl, bl, out);
}

// Round 5
// 279.034 us; speedup vs baseline: 2.2187x; 1.0956x over previous
//
#include <hip/hip_runtime.h>

constexpr int HID = 64;
constexpr int SCAN_NB = 256;   // max blocks for hierarchical scan (196 used)

// ---- int histogram of dst ----
__global__ __launch_bounds__(256) void k_hist(const int* __restrict__ dst, int nE,
                                              int* __restrict__ deg) {
  int i = blockIdx.x * 256 + threadIdx.x;
  if (i < nE) atomicAdd(&deg[dst[i]], 1);
}

__global__ __launch_bounds__(256) void k_dinv(const int* __restrict__ deg,
                                              float* __restrict__ dinv, int nN) {
  int i = blockIdx.x * 256 + threadIdx.x;
  if (i < nN) dinv[i] = rsqrtf((float)deg[i] + 1.0f);   // +1 = self-loop
}

// ---- hierarchical exclusive scan of deg -> row_start (and cursor copy) ----
__global__ __launch_bounds__(256) void k_scanA(const int* __restrict__ deg, int nN,
                                               int* __restrict__ partial) {
  __shared__ int s[256];
  int v = blockIdx.x * 256 + threadIdx.x;
  s[threadIdx.x] = (v < nN) ? deg[v] : 0;
  __syncthreads();
  for (int d = 128; d; d >>= 1) {
    if (threadIdx.x < d) s[threadIdx.x] += s[threadIdx.x + d];
    __syncthreads();
  }
  if (threadIdx.x == 0) partial[blockIdx.x] = s[0];
}

__global__ __launch_bounds__(256) void k_scanB(int* __restrict__ partial, int nB,
                                               int* __restrict__ partial_ex,
                                               int* __restrict__ row_start, int nN) {
  __shared__ int s[256];
  int t = threadIdx.x;
  int own = (t < nB) ? partial[t] : 0;
  s[t] = own;
  __syncthreads();
  for (int d = 1; d < 256; d <<= 1) {
    int x = s[t];
    if (t >= d) x += s[t - d];
    __syncthreads();
    s[t] = x;
    __syncthreads();
  }
  partial_ex[t] = s[t] - own;          // exclusive
  if (t == 255) row_start[nN] = s[255]; // total = nE
}

__global__ __launch_bounds__(256) void k_scanC(const int* __restrict__ deg, int nN,
                                               const int* __restrict__ partial_ex,
                                               int* __restrict__ row_start,
                                               int* __restrict__ cursor) {
  __shared__ int s[256];
  int t = threadIdx.x;
  int v = blockIdx.x * 256 + t;
  int own = (v < nN) ? deg[v] : 0;
  s[t] = own;
  __syncthreads();
  for (int d = 1; d < 256; d <<= 1) {
    int x = s[t];
    if (t >= d) x += s[t - d];
    __syncthreads();
    s[t] = x;
    __syncthreads();
  }
  if (v < nN) {
    int rs = partial_ex[blockIdx.x] + s[t] - own;
    row_start[v] = rs;
    cursor[v] = rs;
  }
}

// ---- CSR fill (order nondeterministic; downstream sums are order-insensitive) ----
__global__ __launch_bounds__(256) void k_fill(const int* __restrict__ src,
                                              const int* __restrict__ dst, int nE,
                                              int* __restrict__ cursor,
                                              int* __restrict__ csr) {
  int e = blockIdx.x * 256 + threadIdx.x;
  if (e < nE) {
    int pos = atomicAdd(&cursor[dst[e]], 1);
    csr[pos] = src[e];
  }
}

// ---- fused matmul + row scale: out[v,c] = dinv[v] * sum_k X[v,k]*W[k,c] ----
// Block = 4 waves; each wave computes 16 rows x 64 cols (lane = col),
// 16 independent accumulator chains, float4 x loads, K stepped by 4.
template <int K>
__global__ __launch_bounds__(256) void k_mm_scale(const float* __restrict__ X,
                                                  const float* __restrict__ W,
                                                  const float* __restrict__ dinv,
                                                  float* __restrict__ out, int nRows) {
  __shared__ float Ws[K * HID];
  for (int t = threadIdx.x; t < K * HID; t += 256) Ws[t] = W[t];
  __syncthreads();
  const int lane = threadIdx.x & 63;
  const int wid  = threadIdx.x >> 6;
  const int row0 = blockIdx.x * 64 + wid * 16;
  if (row0 >= nRows) return;

  float acc[16];
#pragma unroll
  for (int r = 0; r < 16; ++r) acc[r] = 0.f;

  if (row0 + 15 < nRows) {
    for (int k = 0; k < K; k += 4) {
      const float w0 = Ws[(k + 0) * HID + lane];
      const float w1 = Ws[(k + 1) * HID + lane];
      const float w2 = Ws[(k + 2) * HID + lane];
      const float w3 = Ws[(k + 3) * HID + lane];
#pragma unroll
      for (int r = 0; r < 16; ++r) {
        const float4 xv = *(const float4*)(X + (size_t)(row0 + r) * K + k);
        acc[r] = fmaf(xv.x, w0, acc[r]);
        acc[r] = fmaf(xv.y, w1, acc[r]);
        acc[r] = fmaf(xv.z, w2, acc[r]);
        acc[r] = fmaf(xv.w, w3, acc[r]);
      }
    }
#pragma unroll
    for (int r = 0; r < 16; ++r)
      out[(size_t)(row0 + r) * HID + lane] = acc[r] * dinv[row0 + r];
  } else {
    // tail: per-row guarded (not hit when nRows % 16 == 0)
    for (int r = 0; r < 16; ++r) {
      int row = row0 + r;
      if (row >= nRows) break;
      float a = 0.f;
      for (int k = 0; k < K; k += 4) {
        const float4 xv = *(const float4*)(X + (size_t)row * K + k);
        a = fmaf(xv.x, Ws[(k + 0) * HID + lane], a);
        a = fmaf(xv.y, Ws[(k + 1) * HID + lane], a);
        a = fmaf(xv.z, Ws[(k + 2) * HID + lane], a);
        a = fmaf(xv.w, Ws[(k + 3) * HID + lane], a);
      }
      out[(size_t)row * HID + lane] = a * dinv[row];
    }
  }
}

// ---- fused gather + self-loop + epilogue: one wave per node ----
// DOUBLE accumulation: result is independent of CSR neighbor order
// (replay-stable to <=1 fp32 ulp despite the nondeterministic k_fill).
__global__ __launch_bounds__(256) void k_gather_post(const int* __restrict__ csr,
                                                     const int* __restrict__ row_start,
                                                     const float* __restrict__ H,
                                                     const float* __restrict__ dinv,
                                                     const float* __restrict__ b,
                                                     float* __restrict__ out, int nN) {
  int wid = threadIdx.x >> 6;
  int lane = threadIdx.x & 63;
  int v = blockIdx.x * 4 + wid;
  if (v >= nN) return;
  int lo = row_start[v], hi = row_start[v + 1];
  double a0 = (double)H[(size_t)v * HID + lane];   // self-loop
  double a1 = 0.0, a2 = 0.0, a3 = 0.0;
  for (int p = lo; p < hi; p += 64) {
    int n = min(64, hi - p);
    int idx = (p + lane < hi) ? csr[p + lane] : 0;
    int j = 0;
    for (; j + 3 < n; j += 4) {
      int s0 = __shfl(idx, j, 64);
      int s1 = __shfl(idx, j + 1, 64);
      int s2 = __shfl(idx, j + 2, 64);
      int s3 = __shfl(idx, j + 3, 64);
      a0 += (double)H[(size_t)s0 * HID + lane];
      a1 += (double)H[(size_t)s1 * HID + lane];
      a2 += (double)H[(size_t)s2 * HID + lane];
      a3 += (double)H[(size_t)s3 * HID + lane];
    }
    for (; j < n; ++j) {
      int s0 = __shfl(idx, j, 64);
      a0 += (double)H[(size_t)s0 * HID + lane];
    }
  }
  float tot = (float)((a0 + a1) + (a2 + a3));
  out[(size_t)v * HID + lane] = fmaxf(fmaf(dinv[v], tot, b[lane]), 0.f);
}

// ---- pooling + head, atomic-free (batch is sorted): one block per graph ----
__device__ inline int lowerb(const int* __restrict__ a, int n, int key) {
  int lo = 0, hi = n;
  while (lo < hi) {
    int mid = (lo + hi) >> 1;
    if (a[mid] < key) lo = mid + 1; else hi = mid;
  }
  return lo;
}

__global__ __launch_bounds__(256) void k_pool_head(const float* __restrict__ Z,
                                                   const int* __restrict__ batch, int nN,
                                                   const float* __restrict__ Wl,
                                                   const float* __restrict__ bl,
                                                   float* __restrict__ out) {
  int g = blockIdx.x;
  int lane = threadIdx.x & 63;
  int wid = threadIdx.x >> 6;
  int lo = lowerb(batch, nN, g);
  int hi = lowerb(batch, nN, g + 1);
  double acc = 0.0;
  for (int r = lo + wid; r < hi; r += 4) acc += (double)Z[(size_t)r * HID + lane];
  __shared__ double s[4][HID];
  s[wid][lane] = acc;
  __syncthreads();
  if (wid == 0) {
    double tot = (s[0][lane] + s[1][lane]) + (s[2][lane] + s[3][lane]);
    double mean = tot / (double)max(hi - lo, 1);
    double p0 = mean * (double)Wl[lane * 2 + 0];
    double p1 = mean * (double)Wl[lane * 2 + 1];
#pragma unroll
    for (int off = 32; off; off >>= 1) {
      p0 += __shfl_xor(p0, off, 64);
      p1 += __shfl_xor(p1, off, 64);
    }
    if (lane == 0) {
      out[g * 2 + 0] = (float)(p0 + (double)bl[0]);
      out[g * 2 + 1] = (float)(p1 + (double)bl[1]);
    }
  }
}

extern "C" void kernel_launch(void* const* d_in, const int* in_sizes, int n_in,
                              void* d_out, int out_size, void* d_ws, size_t ws_size,
                              hipStream_t stream) {
  const float* x     = (const float*)d_in[0];
  const int*   ei    = (const int*)d_in[1];
  const int*   batch = (const int*)d_in[2];
  const float* W1    = (const float*)d_in[3];
  const float* b1    = (const float*)d_in[4];
  const float* W2    = (const float*)d_in[5];
  const float* b2    = (const float*)d_in[6];
  const float* Wl    = (const float*)d_in[7];
  const float* bl    = (const float*)d_in[8];
  float* out = (float*)d_out;

  const int nN = in_sizes[2];          // 50000
  const int nE = in_sizes[1] / 2;      // 800000
  const int nG = out_size / 2;         // 512
  const int* src = ei;
  const int* dst = ei + nE;

  char* ws = (char*)d_ws;
  size_t off = 0;
  auto alloc = [&](size_t bytes) {
    char* p = ws + off;
    off += (bytes + 255) & ~(size_t)255;
    return p;
  };
  int*   deg       = (int*)alloc((size_t)nN * 4);
  int*   row_start = (int*)alloc(((size_t)nN + 1) * 4);
  int*   cursor    = (int*)alloc((size_t)nN * 4);
  int*   csr       = (int*)alloc((size_t)nE * 4);
  int*   partial   = (int*)alloc(SCAN_NB * 4);
  int*   partialex = (int*)alloc(SCAN_NB * 4);
  float* dinv      = (float*)alloc((size_t)nN * 4);
  float* A         = (float*)alloc((size_t)nN * HID * 4);
  float* B         = (float*)alloc((size_t)nN * HID * 4);

  const int nB = (nN + 255) / 256;     // 196 scan blocks

  // CSR build
  hipMemsetAsync(deg, 0, (size_t)nN * 4, stream);
  k_hist<<<(nE + 255) / 256, 256, 0, stream>>>(dst, nE, deg);
  k_dinv<<<nB, 256, 0, stream>>>(deg, dinv, nN);
  k_scanA<<<nB, 256, 0, stream>>>(deg, nN, partial);
  k_scanB<<<1, 256, 0, stream>>>(partial, nB, partialex, row_start, nN);
  k_scanC<<<nB, 256, 0, stream>>>(deg, nN, partialex, row_start, cursor);
  k_fill<<<(nE + 255) / 256, 256, 0, stream>>>(src, dst, nE, cursor, csr);

  // layer 1: H_s = dinv*(x@W1) ; z1 = relu(dinv*(gather+self)+b1)
  k_mm_scale<128><<<(nN + 63) / 64, 256, 0, stream>>>(x, W1, dinv, A, nN);
  k_gather_post<<<(nN + 3) / 4, 256, 0, stream>>>(csr, row_start, A, dinv, b1, B, nN);

  // layer 2
  k_mm_scale<64><<<(nN + 63) / 64, 256, 0, stream>>>(B, W2, dinv, A, nN);
  k_gather_post<<<(nN + 3) / 4, 256, 0, stream>>>(csr, row_start, A, dinv, b2, B, nN);

  // pooling + head
  k_pool_head<<<nG, 256, 0, stream>>>(B, batch, nN, Wl, bl, out);
}

// Round 6
// 215.519 us; speedup vs baseline: 2.8725x; 1.2947x over previous
//
#include <hip/hip_runtime.h>

constexpr int HID = 64;
constexpr int SCAN_NB = 256;   // max blocks for hierarchical scan (196 used)
constexpr int RB = 128;        // mm block row-tile
constexpr int KC = 32;         // mm K-chunk

// ---- int histogram of dst ----
__global__ __launch_bounds__(256) void k_hist(const int* __restrict__ dst, int nE,
                                              int* __restrict__ deg) {
  int i = blockIdx.x * 256 + threadIdx.x;
  if (i < nE) atomicAdd(&deg[dst[i]], 1);
}

__global__ __launch_bounds__(256) void k_dinv(const int* __restrict__ deg,
                                              float* __restrict__ dinv, int nN) {
  int i = blockIdx.x * 256 + threadIdx.x;
  if (i < nN) dinv[i] = rsqrtf((float)deg[i] + 1.0f);   // +1 = self-loop
}

// ---- hierarchical exclusive scan of deg -> row_start (and cursor copy) ----
__global__ __launch_bounds__(256) void k_scanA(const int* __restrict__ deg, int nN,
                                               int* __restrict__ partial) {
  __shared__ int s[256];
  int v = blockIdx.x * 256 + threadIdx.x;
  s[threadIdx.x] = (v < nN) ? deg[v] : 0;
  __syncthreads();
  for (int d = 128; d; d >>= 1) {
    if (threadIdx.x < d) s[threadIdx.x] += s[threadIdx.x + d];
    __syncthreads();
  }
  if (threadIdx.x == 0) partial[blockIdx.x] = s[0];
}

__global__ __launch_bounds__(256) void k_scanB(int* __restrict__ partial, int nB,
                                               int* __restrict__ partial_ex,
                                               int* __restrict__ row_start, int nN) {
  __shared__ int s[256];
  int t = threadIdx.x;
  int own = (t < nB) ? partial[t] : 0;
  s[t] = own;
  __syncthreads();
  for (int d = 1; d < 256; d <<= 1) {
    int x = s[t];
    if (t >= d) x += s[t - d];
    __syncthreads();
    s[t] = x;
    __syncthreads();
  }
  partial_ex[t] = s[t] - own;          // exclusive
  if (t == 255) row_start[nN] = s[255]; // total = nE
}

__global__ __launch_bounds__(256) void k_scanC(const int* __restrict__ deg, int nN,
                                               const int* __restrict__ partial_ex,
                                               int* __restrict__ row_start,
                                               int* __restrict__ cursor) {
  __shared__ int s[256];
  int t = threadIdx.x;
  int v = blockIdx.x * 256 + t;
  int own = (v < nN) ? deg[v] : 0;
  s[t] = own;
  __syncthreads();
  for (int d = 1; d < 256; d <<= 1) {
    int x = s[t];
    if (t >= d) x += s[t - d];
    __syncthreads();
    s[t] = x;
    __syncthreads();
  }
  if (v < nN) {
    int rs = partial_ex[blockIdx.x] + s[t] - own;
    row_start[v] = rs;
    cursor[v] = rs;
  }
}

// ---- CSR fill (order nondeterministic; downstream sums are order-insensitive) ----
__global__ __launch_bounds__(256) void k_fill(const int* __restrict__ src,
                                              const int* __restrict__ dst, int nE,
                                              int* __restrict__ cursor,
                                              int* __restrict__ csr) {
  int e = blockIdx.x * 256 + threadIdx.x;
  if (e < nE) {
    int pos = atomicAdd(&cursor[dst[e]], 1);
    csr[pos] = src[e];
  }
}

// ---- LDS-tiled matmul + row scale: out[v,c] = dinv[v] * sum_k X[v,k]*W[k,c] ----
// Block = 256 threads = 4 waves; tile RB=128 rows x 64 cols; K chunked by KC=32.
// Wave w owns rows [w*32, w*32+32). Lane: rg=lane>>3 -> 4 rows, cg=lane&7 -> 8 cols.
// Per k: 4x ds_read_b32 (Xs, +1 pad -> conflict-free) + 2x ds_read_b128 (Ws, 2-way free)
// + 32 FMAs -> VALU-bound.
template <int K>
__global__ __launch_bounds__(256) void k_mm_tile(const float* __restrict__ X,
                                                 const float* __restrict__ W,
                                                 const float* __restrict__ dinv,
                                                 float* __restrict__ out, int nRows) {
  __shared__ float Xs[RB][KC + 1];
  __shared__ float Ws[KC][HID];

  const int t    = threadIdx.x;
  const int lane = t & 63;
  const int wid  = t >> 6;
  const int rg   = lane >> 3;       // 0..7 -> 4-row group
  const int cg   = lane & 7;        // 0..7 -> 8-col group
  const int rb   = blockIdx.x * RB;
  const int rloc = wid * 32 + rg * 4;   // row within block tile

  float acc[4][8];
#pragma unroll
  for (int i = 0; i < 4; ++i)
#pragma unroll
    for (int j = 0; j < 8; ++j) acc[i][j] = 0.f;

  for (int c = 0; c < K / KC; ++c) {
    const int k0 = c * KC;
    // ---- stage X chunk: 128 rows x 32 k; thread -> 4 float4 (full 128B lines) ----
    {
      const int r  = t >> 1;            // 0..127
      const int kh = (t & 1) * 16;      // 0 | 16
      const int grow = rb + r;
      if (grow < nRows) {
        const float* p = X + (size_t)grow * K + k0 + kh;
#pragma unroll
        for (int q = 0; q < 4; ++q) {
          const float4 v = *(const float4*)(p + q * 4);
          float* d = &Xs[r][kh + q * 4];
          d[0] = v.x; d[1] = v.y; d[2] = v.z; d[3] = v.w;
        }
      }
    }
    // ---- stage W chunk: 32 k x 64 c; thread -> 8 floats (coalesced 256B rows) ----
    {
      const float* p = W + (size_t)(k0 + (t >> 3)) * HID + (t & 7) * 8;
      const float4 v0 = *(const float4*)p;
      const float4 v1 = *(const float4*)(p + 4);
      float* d = &Ws[t >> 3][(t & 7) * 8];
      ((float4*)d)[0] = v0;
      ((float4*)d)[1] = v1;
    }
    __syncthreads();

    // ---- compute chunk ----
#pragma unroll
    for (int k = 0; k < KC; ++k) {
      const float4 w0 = *(const float4*)&Ws[k][cg * 8];
      const float4 w1 = *(const float4*)&Ws[k][cg * 8 + 4];
      float xv[4];
#pragma unroll
      for (int i = 0; i < 4; ++i) xv[i] = Xs[rloc + i][k];
#pragma unroll
      for (int i = 0; i < 4; ++i) {
        acc[i][0] = fmaf(xv[i], w0.x, acc[i][0]);
        acc[i][1] = fmaf(xv[i], w0.y, acc[i][1]);
        acc[i][2] = fmaf(xv[i], w0.z, acc[i][2]);
        acc[i][3] = fmaf(xv[i], w0.w, acc[i][3]);
        acc[i][4] = fmaf(xv[i], w1.x, acc[i][4]);
        acc[i][5] = fmaf(xv[i], w1.y, acc[i][5]);
        acc[i][6] = fmaf(xv[i], w1.z, acc[i][6]);
        acc[i][7] = fmaf(xv[i], w1.w, acc[i][7]);
      }
    }
    __syncthreads();
  }

  // ---- store with dinv scale (coalesced 32B per lane) ----
#pragma unroll
  for (int i = 0; i < 4; ++i) {
    const int row = rb + rloc + i;
    if (row < nRows) {
      const float s = dinv[row];
      float4 o0, o1;
      o0.x = acc[i][0] * s; o0.y = acc[i][1] * s; o0.z = acc[i][2] * s; o0.w = acc[i][3] * s;
      o1.x = acc[i][4] * s; o1.y = acc[i][5] * s; o1.z = acc[i][6] * s; o1.w = acc[i][7] * s;
      float* p = out + (size_t)row * HID + cg * 8;
      ((float4*)p)[0] = o0;
      ((float4*)p)[1] = o1;
    }
  }
}

// ---- fused gather + self-loop + epilogue: one wave per node ----
// DOUBLE accumulation: result is independent of CSR neighbor order
// (replay-stable to <=1 fp32 ulp despite the nondeterministic k_fill).
__global__ __launch_bounds__(256) void k_gather_post(const int* __restrict__ csr,
                                                     const int* __restrict__ row_start,
                                                     const float* __restrict__ H,
                                                     const float* __restrict__ dinv,
                                                     const float* __restrict__ b,
                                                     float* __restrict__ out, int nN) {
  int wid = threadIdx.x >> 6;
  int lane = threadIdx.x & 63;
  int v = blockIdx.x * 4 + wid;
  if (v >= nN) return;
  int lo = row_start[v], hi = row_start[v + 1];
  double a0 = (double)H[(size_t)v * HID + lane];   // self-loop
  double a1 = 0.0, a2 = 0.0, a3 = 0.0;
  for (int p = lo; p < hi; p += 64) {
    int n = min(64, hi - p);
    int idx = (p + lane < hi) ? csr[p + lane] : 0;
    int j = 0;
    for (; j + 3 < n; j += 4) {
      int s0 = __shfl(idx, j, 64);
      int s1 = __shfl(idx, j + 1, 64);
      int s2 = __shfl(idx, j + 2, 64);
      int s3 = __shfl(idx, j + 3, 64);
      a0 += (double)H[(size_t)s0 * HID + lane];
      a1 += (double)H[(size_t)s1 * HID + lane];
      a2 += (double)H[(size_t)s2 * HID + lane];
      a3 += (double)H[(size_t)s3 * HID + lane];
    }
    for (; j < n; ++j) {
      int s0 = __shfl(idx, j, 64);
      a0 += (double)H[(size_t)s0 * HID + lane];
    }
  }
  float tot = (float)((a0 + a1) + (a2 + a3));
  out[(size_t)v * HID + lane] = fmaxf(fmaf(dinv[v], tot, b[lane]), 0.f);
}

// ---- pooling + head, atomic-free (batch is sorted): one block per graph ----
__device__ inline int lowerb(const int* __restrict__ a, int n, int key) {
  int lo = 0, hi = n;
  while (lo < hi) {
    int mid = (lo + hi) >> 1;
    if (a[mid] < key) lo = mid + 1; else hi = mid;
  }
  return lo;
}

__global__ __launch_bounds__(256) void k_pool_head(const float* __restrict__ Z,
                                                   const int* __restrict__ batch, int nN,
                                                   const float* __restrict__ Wl,
                                                   const float* __restrict__ bl,
                                                   float* __restrict__ out) {
  int g = blockIdx.x;
  int lane = threadIdx.x & 63;
  int wid = threadIdx.x >> 6;
  int lo = lowerb(batch, nN, g);
  int hi = lowerb(batch, nN, g + 1);
  double acc = 0.0;
  for (int r = lo + wid; r < hi; r += 4) acc += (double)Z[(size_t)r * HID + lane];
  __shared__ double s[4][HID];
  s[wid][lane] = acc;
  __syncthreads();
  if (wid == 0) {
    double tot = (s[0][lane] + s[1][lane]) + (s[2][lane] + s[3][lane]);
    double mean = tot / (double)max(hi - lo, 1);
    double p0 = mean * (double)Wl[lane * 2 + 0];
    double p1 = mean * (double)Wl[lane * 2 + 1];
#pragma unroll
    for (int off = 32; off; off >>= 1) {
      p0 += __shfl_xor(p0, off, 64);
      p1 += __shfl_xor(p1, off, 64);
    }
    if (lane == 0) {
      out[g * 2 + 0] = (float)(p0 + (double)bl[0]);
      out[g * 2 + 1] = (float)(p1 + (double)bl[1]);
    }
  }
}

extern "C" void kernel_launch(void* const* d_in, const int* in_sizes, int n_in,
                              void* d_out, int out_size, void* d_ws, size_t ws_size,
                              hipStream_t stream) {
  const float* x     = (const float*)d_in[0];
  const int*   ei    = (const int*)d_in[1];
  const int*   batch = (const int*)d_in[2];
  const float* W1    = (const float*)d_in[3];
  const float* b1    = (const float*)d_in[4];
  const float* W2    = (const float*)d_in[5];
  const float* b2    = (const float*)d_in[6];
  const float* Wl    = (const float*)d_in[7];
  const float* bl    = (const float*)d_in[8];
  float* out = (float*)d_out;

  const int nN = in_sizes[2];          // 50000
  const int nE = in_sizes[1] / 2;      // 800000
  const int nG = out_size / 2;         // 512
  const int* src = ei;
  const int* dst = ei + nE;

  char* ws = (char*)d_ws;
  size_t off = 0;
  auto alloc = [&](size_t bytes) {
    char* p = ws + off;
    off += (bytes + 255) & ~(size_t)255;
    return p;
  };
  int*   deg       = (int*)alloc((size_t)nN * 4);
  int*   row_start = (int*)alloc(((size_t)nN + 1) * 4);
  int*   cursor    = (int*)alloc((size_t)nN * 4);
  int*   csr       = (int*)alloc((size_t)nE * 4);
  int*   partial   = (int*)alloc(SCAN_NB * 4);
  int*   partialex = (int*)alloc(SCAN_NB * 4);
  float* dinv      = (float*)alloc((size_t)nN * 4);
  float* A         = (float*)alloc((size_t)nN * HID * 4);
  float* B         = (float*)alloc((size_t)nN * HID * 4);

  const int nB = (nN + 255) / 256;     // 196 scan blocks

  // CSR build
  hipMemsetAsync(deg, 0, (size_t)nN * 4, stream);
  k_hist<<<(nE + 255) / 256, 256, 0, stream>>>(dst, nE, deg);
  k_dinv<<<nB, 256, 0, stream>>>(deg, dinv, nN);
  k_scanA<<<nB, 256, 0, stream>>>(deg, nN, partial);
  k_scanB<<<1, 256, 0, stream>>>(partial, nB, partialex, row_start, nN);
  k_scanC<<<nB, 256, 0, stream>>>(deg, nN, partialex, row_start, cursor);
  k_fill<<<(nE + 255) / 256, 256, 0, stream>>>(src, dst, nE, cursor, csr);

  // layer 1: H_s = dinv*(x@W1) ; z1 = relu(dinv*(gather+self)+b1)
  k_mm_tile<128><<<(nN + RB - 1) / RB, 256, 0, stream>>>(x, W1, dinv, A, nN);
  k_gather_post<<<(nN + 3) / 4, 256, 0, stream>>>(csr, row_start, A, dinv, b1, B, nN);

  // layer 2
  k_mm_tile<64><<<(nN + RB - 1) / RB, 256, 0, stream>>>(B, W2, dinv, A, nN);
  k_gather_post<<<(nN + 3) / 4, 256, 0, stream>>>(csr, row_start, A, dinv, b2, B, nN);

  // pooling + head
  k_pool_head<<<nG, 256, 0, stream>>>(B, batch, nN, Wl, bl, out);
}

// Round 7
// 196.184 us; speedup vs baseline: 3.1556x; 1.0986x over previous
//
#include <hip/hip_runtime.h>

constexpr int HID = 64;
constexpr int SCAN_NB = 256;   // max blocks for hierarchical scan (196 used)
constexpr int RB = 128;        // mm block row-tile
constexpr int KC = 32;         // mm K-chunk
constexpr int NPB = 128;       // nodes per bucket (pow2: bucket = dst >> 7)
constexpr int MAXBUCK = 512;   // supports nN <= 65536
constexpr int CHUNK = 4096;    // edges per k_bucket block

// ---- int histogram of dst ----
__global__ __launch_bounds__(256) void k_hist(const int* __restrict__ dst, int nE,
                                              int* __restrict__ deg) {
  int i = blockIdx.x * 256 + threadIdx.x;
  if (i < nE) atomicAdd(&deg[dst[i]], 1);
}

__global__ __launch_bounds__(256) void k_dinv(const int* __restrict__ deg,
                                              float* __restrict__ dinv, int nN) {
  int i = blockIdx.x * 256 + threadIdx.x;
  if (i < nN) dinv[i] = rsqrtf((float)deg[i] + 1.0f);   // +1 = self-loop
}

// ---- hierarchical exclusive scan of deg -> row_start ----
__global__ __launch_bounds__(256) void k_scanA(const int* __restrict__ deg, int nN,
                                               int* __restrict__ partial) {
  __shared__ int s[256];
  int v = blockIdx.x * 256 + threadIdx.x;
  s[threadIdx.x] = (v < nN) ? deg[v] : 0;
  __syncthreads();
  for (int d = 128; d; d >>= 1) {
    if (threadIdx.x < d) s[threadIdx.x] += s[threadIdx.x + d];
    __syncthreads();
  }
  if (threadIdx.x == 0) partial[blockIdx.x] = s[0];
}

__global__ __launch_bounds__(256) void k_scanB(int* __restrict__ partial, int nB,
                                               int* __restrict__ partial_ex,
                                               int* __restrict__ row_start, int nN) {
  __shared__ int s[256];
  int t = threadIdx.x;
  int own = (t < nB) ? partial[t] : 0;
  s[t] = own;
  __syncthreads();
  for (int d = 1; d < 256; d <<= 1) {
    int x = s[t];
    if (t >= d) x += s[t - d];
    __syncthreads();
    s[t] = x;
    __syncthreads();
  }
  partial_ex[t] = s[t] - own;          // exclusive
  if (t == 255) row_start[nN] = s[255]; // total = nE
}

__global__ __launch_bounds__(256) void k_scanC(const int* __restrict__ deg, int nN,
                                               const int* __restrict__ partial_ex,
                                               int* __restrict__ row_start) {
  __shared__ int s[256];
  int t = threadIdx.x;
  int v = blockIdx.x * 256 + t;
  int own = (v < nN) ? deg[v] : 0;
  s[t] = own;
  __syncthreads();
  for (int d = 1; d < 256; d <<= 1) {
    int x = s[t];
    if (t >= d) x += s[t - d];
    __syncthreads();
    s[t] = x;
    __syncthreads();
  }
  if (v < nN) row_start[v] = partial_ex[blockIdx.x] + s[t] - own;
}

// ---- CSR build pass 1: bucket (src,dst) pairs into CSR-aligned bucket regions ----
// Block-level LDS histogram + one global reservation per (block,bucket) keeps
// each ~84B reserved range single-owner -> coalesced write-back.
__global__ __launch_bounds__(256) void k_bucket(const int* __restrict__ src,
                                                const int* __restrict__ dst, int nE,
                                                const int* __restrict__ row_start,
                                                int* __restrict__ bucket_cursor,
                                                int2* __restrict__ pairs, int nBuck) {
  __shared__ int hist[MAXBUCK];
  __shared__ int base[MAXBUCK];
  const int t = threadIdx.x;
  const int e0 = blockIdx.x * CHUNK;
  const int eEnd = min(e0 + CHUNK, nE);
  for (int i = t; i < nBuck; i += 256) hist[i] = 0;
  __syncthreads();
  for (int e = e0 + t; e < eEnd; e += 256)
    atomicAdd(&hist[dst[e] >> 7], 1);
  __syncthreads();
  for (int i = t; i < nBuck; i += 256) {
    int c = hist[i];
    int r = (c > 0) ? atomicAdd(&bucket_cursor[i], c) : 0;
    base[i] = row_start[i << 7] + r;   // bucket region base + block's reservation
    hist[i] = 0;
  }
  __syncthreads();
  for (int e = e0 + t; e < eEnd; e += 256) {
    int d = dst[e];
    int b = d >> 7;
    int idx = atomicAdd(&hist[b], 1);
    pairs[base[b] + idx] = make_int2(src[e], d);
  }
}

// ---- CSR build pass 2: one block per bucket, LDS per-node cursors ----
// All csr writes for a bucket come from one block -> lines merged in L2.
__global__ __launch_bounds__(256) void k_place(const int2* __restrict__ pairs,
                                               const int* __restrict__ row_start,
                                               int* __restrict__ csr, int nN) {
  __shared__ int cur[NPB];
  const int t = threadIdx.x;
  const int vbase = blockIdx.x * NPB;
  const int vhi = min(vbase + NPB, nN);
  if (t < NPB && vbase + t < vhi) cur[t] = row_start[vbase + t];
  __syncthreads();
  const int lo = row_start[vbase];
  const int hi = row_start[vhi];
  for (int p = lo + t; p < hi; p += 256) {
    int2 e = pairs[p];
    int pos = atomicAdd(&cur[e.y - vbase], 1);
    csr[pos] = e.x;
  }
}

// ---- LDS-tiled matmul + row scale: out[v,c] = dinv[v] * sum_k X[v,k]*W[k,c] ----
template <int K>
__global__ __launch_bounds__(256) void k_mm_tile(const float* __restrict__ X,
                                                 const float* __restrict__ W,
                                                 const float* __restrict__ dinv,
                                                 float* __restrict__ out, int nRows) {
  __shared__ float Xs[RB][KC + 1];
  __shared__ float Ws[KC][HID];

  const int t    = threadIdx.x;
  const int lane = t & 63;
  const int wid  = t >> 6;
  const int rg   = lane >> 3;       // 0..7 -> 4-row group
  const int cg   = lane & 7;        // 0..7 -> 8-col group
  const int rb   = blockIdx.x * RB;
  const int rloc = wid * 32 + rg * 4;   // row within block tile

  float acc[4][8];
#pragma unroll
  for (int i = 0; i < 4; ++i)
#pragma unroll
    for (int j = 0; j < 8; ++j) acc[i][j] = 0.f;

  for (int c = 0; c < K / KC; ++c) {
    const int k0 = c * KC;
    {
      const int r  = t >> 1;            // 0..127
      const int kh = (t & 1) * 16;      // 0 | 16
      const int grow = rb + r;
      if (grow < nRows) {
        const float* p = X + (size_t)grow * K + k0 + kh;
#pragma unroll
        for (int q = 0; q < 4; ++q) {
          const float4 v = *(const float4*)(p + q * 4);
          float* d = &Xs[r][kh + q * 4];
          d[0] = v.x; d[1] = v.y; d[2] = v.z; d[3] = v.w;
        }
      }
    }
    {
      const float* p = W + (size_t)(k0 + (t >> 3)) * HID + (t & 7) * 8;
      const float4 v0 = *(const float4*)p;
      const float4 v1 = *(const float4*)(p + 4);
      float* d = &Ws[t >> 3][(t & 7) * 8];
      ((float4*)d)[0] = v0;
      ((float4*)d)[1] = v1;
    }
    __syncthreads();

#pragma unroll
    for (int k = 0; k < KC; ++k) {
      const float4 w0 = *(const float4*)&Ws[k][cg * 8];
      const float4 w1 = *(const float4*)&Ws[k][cg * 8 + 4];
      float xv[4];
#pragma unroll
      for (int i = 0; i < 4; ++i) xv[i] = Xs[rloc + i][k];
#pragma unroll
      for (int i = 0; i < 4; ++i) {
        acc[i][0] = fmaf(xv[i], w0.x, acc[i][0]);
        acc[i][1] = fmaf(xv[i], w0.y, acc[i][1]);
        acc[i][2] = fmaf(xv[i], w0.z, acc[i][2]);
        acc[i][3] = fmaf(xv[i], w0.w, acc[i][3]);
        acc[i][4] = fmaf(xv[i], w1.x, acc[i][4]);
        acc[i][5] = fmaf(xv[i], w1.y, acc[i][5]);
        acc[i][6] = fmaf(xv[i], w1.z, acc[i][6]);
        acc[i][7] = fmaf(xv[i], w1.w, acc[i][7]);
      }
    }
    __syncthreads();
  }

#pragma unroll
  for (int i = 0; i < 4; ++i) {
    const int row = rb + rloc + i;
    if (row < nRows) {
      const float s = dinv[row];
      float4 o0, o1;
      o0.x = acc[i][0] * s; o0.y = acc[i][1] * s; o0.z = acc[i][2] * s; o0.w = acc[i][3] * s;
      o1.x = acc[i][4] * s; o1.y = acc[i][5] * s; o1.z = acc[i][6] * s; o1.w = acc[i][7] * s;
      float* p = out + (size_t)row * HID + cg * 8;
      ((float4*)p)[0] = o0;
      ((float4*)p)[1] = o1;
    }
  }
}

// ---- fused gather + self-loop + epilogue: one wave per node ----
// DOUBLE accumulation: result independent of CSR neighbor order.
__global__ __launch_bounds__(256) void k_gather_post(const int* __restrict__ csr,
                                                     const int* __restrict__ row_start,
                                                     const float* __restrict__ H,
                                                     const float* __restrict__ dinv,
                                                     const float* __restrict__ b,
                                                     float* __restrict__ out, int nN) {
  int wid = threadIdx.x >> 6;
  int lane = threadIdx.x & 63;
  int v = blockIdx.x * 4 + wid;
  if (v >= nN) return;
  int lo = row_start[v], hi = row_start[v + 1];
  double a0 = (double)H[(size_t)v * HID + lane];   // self-loop
  double a1 = 0.0, a2 = 0.0, a3 = 0.0;
  for (int p = lo; p < hi; p += 64) {
    int n = min(64, hi - p);
    int idx = (p + lane < hi) ? csr[p + lane] : 0;
    int j = 0;
    for (; j + 3 < n; j += 4) {
      int s0 = __shfl(idx, j, 64);
      int s1 = __shfl(idx, j + 1, 64);
      int s2 = __shfl(idx, j + 2, 64);
      int s3 = __shfl(idx, j + 3, 64);
      a0 += (double)H[(size_t)s0 * HID + lane];
      a1 += (double)H[(size_t)s1 * HID + lane];
      a2 += (double)H[(size_t)s2 * HID + lane];
      a3 += (double)H[(size_t)s3 * HID + lane];
    }
    for (; j < n; ++j) {
      int s0 = __shfl(idx, j, 64);
      a0 += (double)H[(size_t)s0 * HID + lane];
    }
  }
  float tot = (float)((a0 + a1) + (a2 + a3));
  out[(size_t)v * HID + lane] = fmaxf(fmaf(dinv[v], tot, b[lane]), 0.f);
}

// ---- pooling + head, atomic-free (batch is sorted): one block per graph ----
__device__ inline int lowerb(const int* __restrict__ a, int n, int key) {
  int lo = 0, hi = n;
  while (lo < hi) {
    int mid = (lo + hi) >> 1;
    if (a[mid] < key) lo = mid + 1; else hi = mid;
  }
  return lo;
}

__global__ __launch_bounds__(256) void k_pool_head(const float* __restrict__ Z,
                                                   const int* __restrict__ batch, int nN,
                                                   const float* __restrict__ Wl,
                                                   const float* __restrict__ bl,
                                                   float* __restrict__ out) {
  int g = blockIdx.x;
  int lane = threadIdx.x & 63;
  int wid = threadIdx.x >> 6;
  int lo = lowerb(batch, nN, g);
  int hi = lowerb(batch, nN, g + 1);
  double acc = 0.0;
  for (int r = lo + wid; r < hi; r += 4) acc += (double)Z[(size_t)r * HID + lane];
  __shared__ double s[4][HID];
  s[wid][lane] = acc;
  __syncthreads();
  if (wid == 0) {
    double tot = (s[0][lane] + s[1][lane]) + (s[2][lane] + s[3][lane]);
    double mean = tot / (double)max(hi - lo, 1);
    double p0 = mean * (double)Wl[lane * 2 + 0];
    double p1 = mean * (double)Wl[lane * 2 + 1];
#pragma unroll
    for (int off = 32; off; off >>= 1) {
      p0 += __shfl_xor(p0, off, 64);
      p1 += __shfl_xor(p1, off, 64);
    }
    if (lane == 0) {
      out[g * 2 + 0] = (float)(p0 + (double)bl[0]);
      out[g * 2 + 1] = (float)(p1 + (double)bl[1]);
    }
  }
}

extern "C" void kernel_launch(void* const* d_in, const int* in_sizes, int n_in,
                              void* d_out, int out_size, void* d_ws, size_t ws_size,
                              hipStream_t stream) {
  const float* x     = (const float*)d_in[0];
  const int*   ei    = (const int*)d_in[1];
  const int*   batch = (const int*)d_in[2];
  const float* W1    = (const float*)d_in[3];
  const float* b1    = (const float*)d_in[4];
  const float* W2    = (const float*)d_in[5];
  const float* b2    = (const float*)d_in[6];
  const float* Wl    = (const float*)d_in[7];
  const float* bl    = (const float*)d_in[8];
  float* out = (float*)d_out;

  const int nN = in_sizes[2];          // 50000
  const int nE = in_sizes[1] / 2;      // 800000
  const int nG = out_size / 2;         // 512
  const int* src = ei;
  const int* dst = ei + nE;

  char* ws = (char*)d_ws;
  size_t off = 0;
  auto alloc = [&](size_t bytes) {
    char* p = ws + off;
    off += (bytes + 255) & ~(size_t)255;
    return p;
  };
  int*   deg       = (int*)alloc((size_t)nN * 4);
  int*   row_start = (int*)alloc(((size_t)nN + 1) * 4);
  int*   csr       = (int*)alloc((size_t)nE * 4);
  int*   partial   = (int*)alloc(SCAN_NB * 4);
  int*   partialex = (int*)alloc(SCAN_NB * 4);
  int*   bcursor   = (int*)alloc(MAXBUCK * 4);
  float* dinv      = (float*)alloc((size_t)nN * 4);
  float* A         = (float*)alloc((size_t)nN * HID * 4);
  float* B         = (float*)alloc((size_t)nN * HID * 4);
  int2*  pairs     = (int2*)A;         // aliases A: free until mm1 writes it

  const int nB    = (nN + 255) / 256;       // scan blocks
  const int nBuck = (nN + NPB - 1) / NPB;   // 391 buckets

  // CSR build
  hipMemsetAsync(deg, 0, (size_t)nN * 4, stream);
  hipMemsetAsync(bcursor, 0, MAXBUCK * 4, stream);
  k_hist<<<(nE + 255) / 256, 256, 0, stream>>>(dst, nE, deg);
  k_dinv<<<nB, 256, 0, stream>>>(deg, dinv, nN);
  k_scanA<<<nB, 256, 0, stream>>>(deg, nN, partial);
  k_scanB<<<1, 256, 0, stream>>>(partial, nB, partialex, row_start, nN);
  k_scanC<<<nB, 256, 0, stream>>>(deg, nN, partialex, row_start);
  k_bucket<<<(nE + CHUNK - 1) / CHUNK, 256, 0, stream>>>(src, dst, nE, row_start,
                                                         bcursor, pairs, nBuck);
  k_place<<<nBuck, 256, 0, stream>>>(pairs, row_start, csr, nN);

  // layer 1: H_s = dinv*(x@W1) ; z1 = relu(dinv*(gather+self)+b1)
  k_mm_tile<128><<<(nN + RB - 1) / RB, 256, 0, stream>>>(x, W1, dinv, A, nN);
  k_gather_post<<<(nN + 3) / 4, 256, 0, stream>>>(csr, row_start, A, dinv, b1, B, nN);

  // layer 2
  k_mm_tile<64><<<(nN + RB - 1) / RB, 256, 0, stream>>>(B, W2, dinv, A, nN);
  k_gather_post<<<(nN + 3) / 4, 256, 0, stream>>>(csr, row_start, A, dinv, b2, B, nN);

  // pooling + head
  k_pool_head<<<nG, 256, 0, stream>>>(B, batch, nN, Wl, bl, out);
}

// Round 8
// 149.946 us; speedup vs baseline: 4.1287x; 1.3084x over previous
//
#include <hip/hip_runtime.h>

constexpr int HID = 64;
constexpr int RB = 128;        // mm block row-tile
constexpr int KC = 32;         // mm K-chunk
constexpr int NPB = 128;       // nodes per bucket (pow2: bucket = dst >> 7)
constexpr int MAXBUCK = 512;   // supports nN <= 65536
constexpr int CAP = 2560;      // pair slots per bucket (mean 2048 + 11 sigma)
constexpr int CHUNK = 4096;    // edges per k_bucket block

// ---- CSR build pass 1: append (src,dst) pairs into fixed-capacity bucket
// regions. Block-level LDS histogram + one global reservation per
// (block,bucket) keeps each reserved range single-owner -> coalesced. ----
__global__ __launch_bounds__(256) void k_bucket(const int* __restrict__ src,
                                                const int* __restrict__ dst, int nE,
                                                int* __restrict__ bcursor,
                                                int2* __restrict__ pairs, int nBuck) {
  __shared__ int hist[MAXBUCK];
  __shared__ int base[MAXBUCK];
  const int t = threadIdx.x;
  const int e0 = blockIdx.x * CHUNK;
  const int eEnd = min(e0 + CHUNK, nE);
  for (int i = t; i < nBuck; i += 256) hist[i] = 0;
  __syncthreads();
  for (int e = e0 + t; e < eEnd; e += 256)
    atomicAdd(&hist[dst[e] >> 7], 1);
  __syncthreads();
  for (int i = t; i < nBuck; i += 256) {
    int c = hist[i];
    int r = (c > 0) ? atomicAdd(&bcursor[i], c) : 0;
    base[i] = i * CAP + r;
    hist[i] = 0;
  }
  __syncthreads();
  for (int e = e0 + t; e < eEnd; e += 256) {
    int d = dst[e];
    int b = d >> 7;
    int idx = atomicAdd(&hist[b], 1);
    pairs[base[b] + idx] = make_int2(src[e], d);
  }
}

// ---- CSR build pass 2: one block per bucket. LDS histogram -> per-node deg,
// LDS scan -> row bounds + dinv, then local scatter of csr. All csr writes
// for a bucket come from one block -> lines merged in L2. ----
__global__ __launch_bounds__(256) void k_place(const int2* __restrict__ pairs,
                                               const int* __restrict__ bcursor,
                                               int* __restrict__ csr,
                                               int* __restrict__ row_lo,
                                               int* __restrict__ row_hi,
                                               float* __restrict__ dinv, int nN) {
  __shared__ int cnt[NPB], sc[NPB], cur[NPB];
  const int t = threadIdx.x;
  const int b = blockIdx.x;
  const int vbase = b * NPB;
  const int lo = b * CAP;
  const int npairs = bcursor[b];
  if (t < NPB) cnt[t] = 0;
  __syncthreads();
  for (int p = t; p < npairs; p += 256)
    atomicAdd(&cnt[pairs[lo + p].y - vbase], 1);
  __syncthreads();
  if (t < NPB) sc[t] = cnt[t];
  __syncthreads();
  for (int d = 1; d < NPB; d <<= 1) {
    int x = 0;
    if (t < NPB) { x = sc[t]; if (t >= d) x += sc[t - d]; }
    __syncthreads();
    if (t < NPB) sc[t] = x;
    __syncthreads();
  }
  if (t < NPB && vbase + t < nN) {
    int ex = sc[t] - cnt[t];
    row_lo[vbase + t] = lo + ex;
    row_hi[vbase + t] = lo + sc[t];
    dinv[vbase + t] = rsqrtf((float)cnt[t] + 1.0f);   // +1 = self-loop
    cur[t] = lo + ex;
  }
  __syncthreads();
  for (int p = t; p < npairs; p += 256) {
    int2 e = pairs[lo + p];
    int pos = atomicAdd(&cur[e.y - vbase], 1);
    csr[pos] = e.x;
  }
}

// ---- LDS-tiled matmul + row scale: out[v,c] = dinv[v] * sum_k X[v,k]*W[k,c] ----
template <int K>
__global__ __launch_bounds__(256) void k_mm_tile(const float* __restrict__ X,
                                                 const float* __restrict__ W,
                                                 const float* __restrict__ dinv,
                                                 float* __restrict__ out, int nRows) {
  __shared__ float Xs[RB][KC + 1];
  __shared__ float Ws[KC][HID];

  const int t    = threadIdx.x;
  const int lane = t & 63;
  const int wid  = t >> 6;
  const int rg   = lane >> 3;
  const int cg   = lane & 7;
  const int rb   = blockIdx.x * RB;
  const int rloc = wid * 32 + rg * 4;

  float acc[4][8];
#pragma unroll
  for (int i = 0; i < 4; ++i)
#pragma unroll
    for (int j = 0; j < 8; ++j) acc[i][j] = 0.f;

  for (int c = 0; c < K / KC; ++c) {
    const int k0 = c * KC;
    {
      const int r  = t >> 1;
      const int kh = (t & 1) * 16;
      const int grow = rb + r;
      if (grow < nRows) {
        const float* p = X + (size_t)grow * K + k0 + kh;
#pragma unroll
        for (int q = 0; q < 4; ++q) {
          const float4 v = *(const float4*)(p + q * 4);
          float* d = &Xs[r][kh + q * 4];
          d[0] = v.x; d[1] = v.y; d[2] = v.z; d[3] = v.w;
        }
      }
    }
    {
      const float* p = W + (size_t)(k0 + (t >> 3)) * HID + (t & 7) * 8;
      const float4 v0 = *(const float4*)p;
      const float4 v1 = *(const float4*)(p + 4);
      float* d = &Ws[t >> 3][(t & 7) * 8];
      ((float4*)d)[0] = v0;
      ((float4*)d)[1] = v1;
    }
    __syncthreads();

#pragma unroll
    for (int k = 0; k < KC; ++k) {
      const float4 w0 = *(const float4*)&Ws[k][cg * 8];
      const float4 w1 = *(const float4*)&Ws[k][cg * 8 + 4];
      float xv[4];
#pragma unroll
      for (int i = 0; i < 4; ++i) xv[i] = Xs[rloc + i][k];
#pragma unroll
      for (int i = 0; i < 4; ++i) {
        acc[i][0] = fmaf(xv[i], w0.x, acc[i][0]);
        acc[i][1] = fmaf(xv[i], w0.y, acc[i][1]);
        acc[i][2] = fmaf(xv[i], w0.z, acc[i][2]);
        acc[i][3] = fmaf(xv[i], w0.w, acc[i][3]);
        acc[i][4] = fmaf(xv[i], w1.x, acc[i][4]);
        acc[i][5] = fmaf(xv[i], w1.y, acc[i][5]);
        acc[i][6] = fmaf(xv[i], w1.z, acc[i][6]);
        acc[i][7] = fmaf(xv[i], w1.w, acc[i][7]);
      }
    }
    __syncthreads();
  }

#pragma unroll
  for (int i = 0; i < 4; ++i) {
    const int row = rb + rloc + i;
    if (row < nRows) {
      const float s = dinv[row];
      float4 o0, o1;
      o0.x = acc[i][0] * s; o0.y = acc[i][1] * s; o0.z = acc[i][2] * s; o0.w = acc[i][3] * s;
      o1.x = acc[i][4] * s; o1.y = acc[i][5] * s; o1.z = acc[i][6] * s; o1.w = acc[i][7] * s;
      float* p = out + (size_t)row * HID + cg * 8;
      ((float4*)p)[0] = o0;
      ((float4*)p)[1] = o1;
    }
  }
}

// ---- fused gather + self-loop + epilogue, high-MLP version ----
// 16 lanes per node (float4 each -> one coalesced 256B row read), 4 nodes
// per wave, 4 f64 chains per node -> 16 outstanding row loads per wave.
// DOUBLE accumulation keeps the result independent of CSR neighbor order.
__global__ __launch_bounds__(256) void k_gather4(const int* __restrict__ csr,
                                                 const int* __restrict__ row_lo,
                                                 const int* __restrict__ row_hi,
                                                 const float4* __restrict__ H4,
                                                 const float* __restrict__ dinv,
                                                 const float* __restrict__ b,
                                                 float4* __restrict__ out4, int nN) {
  const int t = threadIdx.x;
  const int wid = t >> 6;
  const int lane = t & 63;
  const int ng = lane >> 4;      // node slot within wave (0..3)
  const int cq = lane & 15;      // float4 column (0..15)
  const int v = blockIdx.x * 16 + wid * 4 + ng;
  const int vv = min(v, nN - 1);
  const int lo = row_lo[vv];
  const int cnt = row_hi[vv] - lo;

  double acc[4][4];
#pragma unroll
  for (int c = 0; c < 4; ++c)
#pragma unroll
    for (int q = 0; q < 4; ++q) acc[c][q] = 0.0;
  {
    const float4 sv = H4[(size_t)vv * 16 + cq];   // self-loop
    acc[0][0] = (double)sv.x; acc[0][1] = (double)sv.y;
    acc[0][2] = (double)sv.z; acc[0][3] = (double)sv.w;
  }

  for (int base = 0; base < cnt; base += 16) {
    int idxv = (base + cq < cnt) ? csr[lo + base + cq] : 0;
#pragma unroll
    for (int j = 0; j < 16; ++j) {
      int s = __shfl(idxv, (ng << 4) + j, 64);
      if (base + j < cnt) {
        const float4 h = H4[(size_t)s * 16 + cq];
        acc[j & 3][0] += (double)h.x;
        acc[j & 3][1] += (double)h.y;
        acc[j & 3][2] += (double)h.z;
        acc[j & 3][3] += (double)h.w;
      }
    }
  }

  if (v < nN) {
    const float dv = dinv[v];
    const float4 bb = ((const float4*)b)[cq];
    float4 o;
    o.x = fmaxf(fmaf(dv, (float)((acc[0][0] + acc[1][0]) + (acc[2][0] + acc[3][0])), bb.x), 0.f);
    o.y = fmaxf(fmaf(dv, (float)((acc[0][1] + acc[1][1]) + (acc[2][1] + acc[3][1])), bb.y), 0.f);
    o.z = fmaxf(fmaf(dv, (float)((acc[0][2] + acc[1][2]) + (acc[2][2] + acc[3][2])), bb.z), 0.f);
    o.w = fmaxf(fmaf(dv, (float)((acc[0][3] + acc[1][3]) + (acc[2][3] + acc[3][3])), bb.w), 0.f);
    out4[(size_t)v * 16 + cq] = o;
  }
}

// ---- pooling + head, atomic-free (batch is sorted): one block per graph ----
__device__ inline int lowerb(const int* __restrict__ a, int n, int key) {
  int lo = 0, hi = n;
  while (lo < hi) {
    int mid = (lo + hi) >> 1;
    if (a[mid] < key) lo = mid + 1; else hi = mid;
  }
  return lo;
}

__global__ __launch_bounds__(256) void k_pool_head(const float* __restrict__ Z,
                                                   const int* __restrict__ batch, int nN,
                                                   const float* __restrict__ Wl,
                                                   const float* __restrict__ bl,
                                                   float* __restrict__ out) {
  int g = blockIdx.x;
  int lane = threadIdx.x & 63;
  int wid = threadIdx.x >> 6;
  int lo = lowerb(batch, nN, g);
  int hi = lowerb(batch, nN, g + 1);
  double acc = 0.0;
  for (int r = lo + wid; r < hi; r += 4) acc += (double)Z[(size_t)r * HID + lane];
  __shared__ double s[4][HID];
  s[wid][lane] = acc;
  __syncthreads();
  if (wid == 0) {
    double tot = (s[0][lane] + s[1][lane]) + (s[2][lane] + s[3][lane]);
    double mean = tot / (double)max(hi - lo, 1);
    double p0 = mean * (double)Wl[lane * 2 + 0];
    double p1 = mean * (double)Wl[lane * 2 + 1];
#pragma unroll
    for (int off = 32; off; off >>= 1) {
      p0 += __shfl_xor(p0, off, 64);
      p1 += __shfl_xor(p1, off, 64);
    }
    if (lane == 0) {
      out[g * 2 + 0] = (float)(p0 + (double)bl[0]);
      out[g * 2 + 1] = (float)(p1 + (double)bl[1]);
    }
  }
}

extern "C" void kernel_launch(void* const* d_in, const int* in_sizes, int n_in,
                              void* d_out, int out_size, void* d_ws, size_t ws_size,
                              hipStream_t stream) {
  const float* x     = (const float*)d_in[0];
  const int*   ei    = (const int*)d_in[1];
  const int*   batch = (const int*)d_in[2];
  const float* W1    = (const float*)d_in[3];
  const float* b1    = (const float*)d_in[4];
  const float* W2    = (const float*)d_in[5];
  const float* b2    = (const float*)d_in[6];
  const float* Wl    = (const float*)d_in[7];
  const float* bl    = (const float*)d_in[8];
  float* out = (float*)d_out;

  const int nN = in_sizes[2];          // 50000
  const int nE = in_sizes[1] / 2;      // 800000
  const int nG = out_size / 2;         // 512
  const int* src = ei;
  const int* dst = ei + nE;

  char* ws = (char*)d_ws;
  size_t off = 0;
  auto alloc = [&](size_t bytes) {
    char* p = ws + off;
    off += (bytes + 255) & ~(size_t)255;
    return p;
  };
  int*   bcursor = (int*)alloc(MAXBUCK * 4);
  int*   row_lo  = (int*)alloc((size_t)nN * 4);
  int*   row_hi  = (int*)alloc((size_t)nN * 4);
  int*   csr     = (int*)alloc((size_t)MAXBUCK * CAP * 4);
  float* dinv    = (float*)alloc((size_t)nN * 4);
  float* A       = (float*)alloc((size_t)nN * HID * 4);
  float* B       = (float*)alloc((size_t)nN * HID * 4);
  int2*  pairs   = (int2*)A;           // aliases A: consumed before mm1 writes A

  const int nBuck = (nN + NPB - 1) / NPB;   // 391 buckets

  // CSR build (3 dispatches)
  hipMemsetAsync(bcursor, 0, MAXBUCK * 4, stream);
  k_bucket<<<(nE + CHUNK - 1) / CHUNK, 256, 0, stream>>>(src, dst, nE, bcursor, pairs, nBuck);
  k_place<<<nBuck, 256, 0, stream>>>(pairs, bcursor, csr, row_lo, row_hi, dinv, nN);

  // layer 1: H_s = dinv*(x@W1) ; z1 = relu(dinv*(gather+self)+b1)
  k_mm_tile<128><<<(nN + RB - 1) / RB, 256, 0, stream>>>(x, W1, dinv, A, nN);
  k_gather4<<<(nN + 15) / 16, 256, 0, stream>>>(csr, row_lo, row_hi, (const float4*)A,
                                                dinv, b1, (float4*)B, nN);

  // layer 2
  k_mm_tile<64><<<(nN + RB - 1) / RB, 256, 0, stream>>>(B, W2, dinv, A, nN);
  k_gather4<<<(nN + 15) / 16, 256, 0, stream>>>(csr, row_lo, row_hi, (const float4*)A,
                                                dinv, b2, (float4*)B, nN);

  // pooling + head
  k_pool_head<<<nG, 256, 0, stream>>>(B, batch, nN, Wl, bl, out);
}

// Round 9
// 140.123 us; speedup vs baseline: 4.4181x; 1.0701x over previous
//
#include <hip/hip_runtime.h>

constexpr int HID = 64;
constexpr int RB = 128;        // mm block row-tile
constexpr int KC = 32;         // mm K-chunk
constexpr int NPB = 128;       // nodes per bucket (pow2: bucket = dst >> 7)
constexpr int MAXBUCK = 512;   // supports nN <= 65536
constexpr int CAP = 2560;      // pair slots per bucket (mean 2048 + 11 sigma)
constexpr int CHUNK = 2048;    // edges per k_bucket block (391 blocks)

// ---- CSR build pass 1: append (src,dst) pairs into fixed-capacity bucket
// regions. Block-level LDS histogram + one global reservation per
// (block,bucket) keeps each reserved range single-owner -> coalesced. ----
__global__ __launch_bounds__(256) void k_bucket(const int* __restrict__ src,
                                                const int* __restrict__ dst, int nE,
                                                int* __restrict__ bcursor,
                                                int2* __restrict__ pairs, int nBuck) {
  __shared__ int hist[MAXBUCK];
  __shared__ int base[MAXBUCK];
  const int t = threadIdx.x;
  const int e0 = blockIdx.x * CHUNK;
  const int eEnd = min(e0 + CHUNK, nE);
  for (int i = t; i < nBuck; i += 256) hist[i] = 0;
  __syncthreads();
  for (int e = e0 + t; e < eEnd; e += 256)
    atomicAdd(&hist[dst[e] >> 7], 1);
  __syncthreads();
  for (int i = t; i < nBuck; i += 256) {
    int c = hist[i];
    int r = (c > 0) ? atomicAdd(&bcursor[i], c) : 0;
    base[i] = i * CAP + r;
    hist[i] = 0;
  }
  __syncthreads();
  for (int e = e0 + t; e < eEnd; e += 256) {
    int d = dst[e];
    int b = d >> 7;
    int idx = atomicAdd(&hist[b], 1);
    pairs[base[b] + idx] = make_int2(src[e], d);
  }
}

// ---- CSR build pass 2: one block per bucket. LDS histogram -> per-node deg,
// LDS scan -> row bounds + dinv, then local scatter of csr. ----
__global__ __launch_bounds__(256) void k_place(const int2* __restrict__ pairs,
                                               const int* __restrict__ bcursor,
                                               int* __restrict__ csr,
                                               int* __restrict__ row_lo,
                                               int* __restrict__ row_hi,
                                               float* __restrict__ dinv, int nN) {
  __shared__ int cnt[NPB], sc[NPB], cur[NPB];
  const int t = threadIdx.x;
  const int b = blockIdx.x;
  const int vbase = b * NPB;
  const int lo = b * CAP;
  const int npairs = bcursor[b];
  if (t < NPB) cnt[t] = 0;
  __syncthreads();
  for (int p = t; p < npairs; p += 256)
    atomicAdd(&cnt[pairs[lo + p].y - vbase], 1);
  __syncthreads();
  if (t < NPB) sc[t] = cnt[t];
  __syncthreads();
  for (int d = 1; d < NPB; d <<= 1) {
    int x = 0;
    if (t < NPB) { x = sc[t]; if (t >= d) x += sc[t - d]; }
    __syncthreads();
    if (t < NPB) sc[t] = x;
    __syncthreads();
  }
  if (t < NPB && vbase + t < nN) {
    int ex = sc[t] - cnt[t];
    row_lo[vbase + t] = lo + ex;
    row_hi[vbase + t] = lo + sc[t];
    dinv[vbase + t] = rsqrtf((float)cnt[t] + 1.0f);   // +1 = self-loop
    cur[t] = lo + ex;
  }
  __syncthreads();
  for (int p = t; p < npairs; p += 256) {
    int2 e = pairs[lo + p];
    int pos = atomicAdd(&cur[e.y - vbase], 1);
    csr[pos] = e.x;
  }
}

// ---- LDS-tiled matmul + row scale: out[v,c] = dinv[v] * sum_k X[v,k]*W[k,c] ----
template <int K>
__global__ __launch_bounds__(256) void k_mm_tile(const float* __restrict__ X,
                                                 const float* __restrict__ W,
                                                 const float* __restrict__ dinv,
                                                 float* __restrict__ out, int nRows) {
  __shared__ float Xs[RB][KC + 1];
  __shared__ float Ws[KC][HID];

  const int t    = threadIdx.x;
  const int lane = t & 63;
  const int wid  = t >> 6;
  const int rg   = lane >> 3;
  const int cg   = lane & 7;
  const int rb   = blockIdx.x * RB;
  const int rloc = wid * 32 + rg * 4;

  float acc[4][8];
#pragma unroll
  for (int i = 0; i < 4; ++i)
#pragma unroll
    for (int j = 0; j < 8; ++j) acc[i][j] = 0.f;

  for (int c = 0; c < K / KC; ++c) {
    const int k0 = c * KC;
    {
      const int r  = t >> 1;
      const int kh = (t & 1) * 16;
      const int grow = rb + r;
      if (grow < nRows) {
        const float* p = X + (size_t)grow * K + k0 + kh;
#pragma unroll
        for (int q = 0; q < 4; ++q) {
          const float4 v = *(const float4*)(p + q * 4);
          float* d = &Xs[r][kh + q * 4];
          d[0] = v.x; d[1] = v.y; d[2] = v.z; d[3] = v.w;
        }
      }
    }
    {
      const float* p = W + (size_t)(k0 + (t >> 3)) * HID + (t & 7) * 8;
      const float4 v0 = *(const float4*)p;
      const float4 v1 = *(const float4*)(p + 4);
      float* d = &Ws[t >> 3][(t & 7) * 8];
      ((float4*)d)[0] = v0;
      ((float4*)d)[1] = v1;
    }
    __syncthreads();

#pragma unroll
    for (int k = 0; k < KC; ++k) {
      const float4 w0 = *(const float4*)&Ws[k][cg * 8];
      const float4 w1 = *(const float4*)&Ws[k][cg * 8 + 4];
      float xv[4];
#pragma unroll
      for (int i = 0; i < 4; ++i) xv[i] = Xs[rloc + i][k];
#pragma unroll
      for (int i = 0; i < 4; ++i) {
        acc[i][0] = fmaf(xv[i], w0.x, acc[i][0]);
        acc[i][1] = fmaf(xv[i], w0.y, acc[i][1]);
        acc[i][2] = fmaf(xv[i], w0.z, acc[i][2]);
        acc[i][3] = fmaf(xv[i], w0.w, acc[i][3]);
        acc[i][4] = fmaf(xv[i], w1.x, acc[i][4]);
        acc[i][5] = fmaf(xv[i], w1.y, acc[i][5]);
        acc[i][6] = fmaf(xv[i], w1.z, acc[i][6]);
        acc[i][7] = fmaf(xv[i], w1.w, acc[i][7]);
      }
    }
    __syncthreads();
  }

#pragma unroll
  for (int i = 0; i < 4; ++i) {
    const int row = rb + rloc + i;
    if (row < nRows) {
      const float s = dinv[row];
      float4 o0, o1;
      o0.x = acc[i][0] * s; o0.y = acc[i][1] * s; o0.z = acc[i][2] * s; o0.w = acc[i][3] * s;
      o1.x = acc[i][4] * s; o1.y = acc[i][5] * s; o1.z = acc[i][6] * s; o1.w = acc[i][7] * s;
      float* p = out + (size_t)row * HID + cg * 8;
      ((float4*)p)[0] = o0;
      ((float4*)p)[1] = o1;
    }
  }
}

// ---- fused gather + epilogue + 64x64 matmul (layer1 agg + mm2) ----
// 16 lanes per node, 4 nodes/wave, double-acc gather (order-insensitive),
// then z1 staged in LDS (wave-internal) and multiplied by LDS-resident W2:
// out[v] = dinv[v] * (relu(dinv[v]*gather + b1) @ W2). Compute hides under
// the neighbor-load latency this kernel is bound by.
__global__ __launch_bounds__(256) void k_gather_mm(const int* __restrict__ csr,
                                                   const int* __restrict__ row_lo,
                                                   const int* __restrict__ row_hi,
                                                   const float4* __restrict__ H4,
                                                   const float* __restrict__ dinv,
                                                   const float* __restrict__ b,
                                                   const float* __restrict__ W2,
                                                   float4* __restrict__ out4, int nN) {
  __shared__ float W2s[HID][HID];     // 16 KB
  __shared__ float z1s[16][68];       // padded: group stride 68 -> bank-clean

  const int t = threadIdx.x;
  for (int i = t; i < HID * HID / 4; i += 256)
    ((float4*)W2s)[i] = ((const float4*)W2)[i];
  __syncthreads();

  const int wid = t >> 6;
  const int lane = t & 63;
  const int ng = lane >> 4;      // node slot within wave (0..3)
  const int cq = lane & 15;      // float4 column (0..15)
  const int nl = wid * 4 + ng;   // node slot within block (0..15)
  const int v = blockIdx.x * 16 + nl;
  const int vv = min(v, nN - 1);
  const int lo = row_lo[vv];
  const int cnt = row_hi[vv] - lo;

  double acc[4][4];
#pragma unroll
  for (int c = 0; c < 4; ++c)
#pragma unroll
    for (int q = 0; q < 4; ++q) acc[c][q] = 0.0;
  {
    const float4 sv = H4[(size_t)vv * 16 + cq];   // self-loop
    acc[0][0] = (double)sv.x; acc[0][1] = (double)sv.y;
    acc[0][2] = (double)sv.z; acc[0][3] = (double)sv.w;
  }

  for (int base = 0; base < cnt; base += 16) {
    int idxv = (base + cq < cnt) ? csr[lo + base + cq] : 0;
#pragma unroll
    for (int j = 0; j < 16; ++j) {
      int s = __shfl(idxv, (ng << 4) + j, 64);
      if (base + j < cnt) {
        const float4 h = H4[(size_t)s * 16 + cq];
        acc[j & 3][0] += (double)h.x;
        acc[j & 3][1] += (double)h.y;
        acc[j & 3][2] += (double)h.z;
        acc[j & 3][3] += (double)h.w;
      }
    }
  }

  // z1 = relu(dinv*gather + b1), staged to LDS (wave-internal, no barrier)
  {
    const float dv = dinv[vv];
    const float4 bb = ((const float4*)b)[cq];
    float4 z;
    z.x = fmaxf(fmaf(dv, (float)((acc[0][0] + acc[1][0]) + (acc[2][0] + acc[3][0])), bb.x), 0.f);
    z.y = fmaxf(fmaf(dv, (float)((acc[0][1] + acc[1][1]) + (acc[2][1] + acc[3][1])), bb.y), 0.f);
    z.z = fmaxf(fmaf(dv, (float)((acc[0][2] + acc[1][2]) + (acc[2][2] + acc[3][2])), bb.z), 0.f);
    z.w = fmaxf(fmaf(dv, (float)((acc[0][3] + acc[1][3]) + (acc[2][3] + acc[3][3])), bb.w), 0.f);
    float* zp = &z1s[nl][cq * 4];
    zp[0] = z.x; zp[1] = z.y; zp[2] = z.z; zp[3] = z.w;
  }

  // h2s[v, cq*4..cq*4+3] = dinv[v] * (z1[v] @ W2)
  float h0 = 0.f, h1 = 0.f, h2 = 0.f, h3 = 0.f;
#pragma unroll 8
  for (int k = 0; k < HID; ++k) {
    const float zk = z1s[nl][k];                       // broadcast in group
    const float4 w = *(const float4*)&W2s[k][cq * 4];
    h0 = fmaf(zk, w.x, h0);
    h1 = fmaf(zk, w.y, h1);
    h2 = fmaf(zk, w.z, h2);
    h3 = fmaf(zk, w.w, h3);
  }

  if (v < nN) {
    const float dv = dinv[v];
    float4 o;
    o.x = h0 * dv; o.y = h1 * dv; o.z = h2 * dv; o.w = h3 * dv;
    out4[(size_t)v * 16 + cq] = o;
  }
}

// ---- layer-2 gather + epilogue (as round 8's k_gather4) ----
__global__ __launch_bounds__(256) void k_gather4(const int* __restrict__ csr,
                                                 const int* __restrict__ row_lo,
                                                 const int* __restrict__ row_hi,
                                                 const float4* __restrict__ H4,
                                                 const float* __restrict__ dinv,
                                                 const float* __restrict__ b,
                                                 float4* __restrict__ out4, int nN) {
  const int t = threadIdx.x;
  const int wid = t >> 6;
  const int lane = t & 63;
  const int ng = lane >> 4;
  const int cq = lane & 15;
  const int v = blockIdx.x * 16 + wid * 4 + ng;
  const int vv = min(v, nN - 1);
  const int lo = row_lo[vv];
  const int cnt = row_hi[vv] - lo;

  double acc[4][4];
#pragma unroll
  for (int c = 0; c < 4; ++c)
#pragma unroll
    for (int q = 0; q < 4; ++q) acc[c][q] = 0.0;
  {
    const float4 sv = H4[(size_t)vv * 16 + cq];
    acc[0][0] = (double)sv.x; acc[0][1] = (double)sv.y;
    acc[0][2] = (double)sv.z; acc[0][3] = (double)sv.w;
  }

  for (int base = 0; base < cnt; base += 16) {
    int idxv = (base + cq < cnt) ? csr[lo + base + cq] : 0;
#pragma unroll
    for (int j = 0; j < 16; ++j) {
      int s = __shfl(idxv, (ng << 4) + j, 64);
      if (base + j < cnt) {
        const float4 h = H4[(size_t)s * 16 + cq];
        acc[j & 3][0] += (double)h.x;
        acc[j & 3][1] += (double)h.y;
        acc[j & 3][2] += (double)h.z;
        acc[j & 3][3] += (double)h.w;
      }
    }
  }

  if (v < nN) {
    const float dv = dinv[v];
    const float4 bb = ((const float4*)b)[cq];
    float4 o;
    o.x = fmaxf(fmaf(dv, (float)((acc[0][0] + acc[1][0]) + (acc[2][0] + acc[3][0])), bb.x), 0.f);
    o.y = fmaxf(fmaf(dv, (float)((acc[0][1] + acc[1][1]) + (acc[2][1] + acc[3][1])), bb.y), 0.f);
    o.z = fmaxf(fmaf(dv, (float)((acc[0][2] + acc[1][2]) + (acc[2][2] + acc[3][2])), bb.z), 0.f);
    o.w = fmaxf(fmaf(dv, (float)((acc[0][3] + acc[1][3]) + (acc[2][3] + acc[3][3])), bb.w), 0.f);
    out4[(size_t)v * 16 + cq] = o;
  }
}

// ---- pooling + head, atomic-free (batch is sorted): one block per graph ----
__device__ inline int lowerb(const int* __restrict__ a, int n, int key) {
  int lo = 0, hi = n;
  while (lo < hi) {
    int mid = (lo + hi) >> 1;
    if (a[mid] < key) lo = mid + 1; else hi = mid;
  }
  return lo;
}

__global__ __launch_bounds__(256) void k_pool_head(const float* __restrict__ Z,
                                                   const int* __restrict__ batch, int nN,
                                                   const float* __restrict__ Wl,
                                                   const float* __restrict__ bl,
                                                   float* __restrict__ out) {
  int g = blockIdx.x;
  int lane = threadIdx.x & 63;
  int wid = threadIdx.x >> 6;
  int lo = lowerb(batch, nN, g);
  int hi = lowerb(batch, nN, g + 1);
  double acc = 0.0;
  for (int r = lo + wid; r < hi; r += 4) acc += (double)Z[(size_t)r * HID + lane];
  __shared__ double s[4][HID];
  s[wid][lane] = acc;
  __syncthreads();
  if (wid == 0) {
    double tot = (s[0][lane] + s[1][lane]) + (s[2][lane] + s[3][lane]);
    double mean = tot / (double)max(hi - lo, 1);
    double p0 = mean * (double)Wl[lane * 2 + 0];
    double p1 = mean * (double)Wl[lane * 2 + 1];
#pragma unroll
    for (int off = 32; off; off >>= 1) {
      p0 += __shfl_xor(p0, off, 64);
      p1 += __shfl_xor(p1, off, 64);
    }
    if (lane == 0) {
      out[g * 2 + 0] = (float)(p0 + (double)bl[0]);
      out[g * 2 + 1] = (float)(p1 + (double)bl[1]);
    }
  }
}

extern "C" void kernel_launch(void* const* d_in, const int* in_sizes, int n_in,
                              void* d_out, int out_size, void* d_ws, size_t ws_size,
                              hipStream_t stream) {
  const float* x     = (const float*)d_in[0];
  const int*   ei    = (const int*)d_in[1];
  const int*   batch = (const int*)d_in[2];
  const float* W1    = (const float*)d_in[3];
  const float* b1    = (const float*)d_in[4];
  const float* W2    = (const float*)d_in[5];
  const float* b2    = (const float*)d_in[6];
  const float* Wl    = (const float*)d_in[7];
  const float* bl    = (const float*)d_in[8];
  float* out = (float*)d_out;

  const int nN = in_sizes[2];          // 50000
  const int nE = in_sizes[1] / 2;      // 800000
  const int nG = out_size / 2;         // 512
  const int* src = ei;
  const int* dst = ei + nE;

  char* ws = (char*)d_ws;
  size_t off = 0;
  auto alloc = [&](size_t bytes) {
    char* p = ws + off;
    off += (bytes + 255) & ~(size_t)255;
    return p;
  };
  int*   bcursor = (int*)alloc(MAXBUCK * 4);
  int*   row_lo  = (int*)alloc((size_t)nN * 4);
  int*   row_hi  = (int*)alloc((size_t)nN * 4);
  int*   csr     = (int*)alloc((size_t)MAXBUCK * CAP * 4);
  float* dinv    = (float*)alloc((size_t)nN * 4);
  float* A       = (float*)alloc((size_t)nN * HID * 4);
  float* B       = (float*)alloc((size_t)nN * HID * 4);
  int2*  pairs   = (int2*)A;           // aliases A: consumed before mm1 writes A

  const int nBuck = (nN + NPB - 1) / NPB;   // 391 buckets

  // CSR build
  hipMemsetAsync(bcursor, 0, MAXBUCK * 4, stream);
  k_bucket<<<(nE + CHUNK - 1) / CHUNK, 256, 0, stream>>>(src, dst, nE, bcursor, pairs, nBuck);
  k_place<<<nBuck, 256, 0, stream>>>(pairs, bcursor, csr, row_lo, row_hi, dinv, nN);

  // layer 1 matmul: A = dinv * (x @ W1)
  k_mm_tile<128><<<(nN + RB - 1) / RB, 256, 0, stream>>>(x, W1, dinv, A, nN);

  // fused layer-1 aggregation + mm2: B = dinv * (relu(dinv*agg(A)+b1) @ W2)
  k_gather_mm<<<(nN + 15) / 16, 256, 0, stream>>>(csr, row_lo, row_hi, (const float4*)A,
                                                  dinv, b1, W2, (float4*)B, nN);

  // layer 2 aggregation: A = relu(dinv*agg(B)+b2)
  k_gather4<<<(nN + 15) / 16, 256, 0, stream>>>(csr, row_lo, row_hi, (const float4*)B,
                                                dinv, b2, (float4*)A, nN);

  // pooling + head
  k_pool_head<<<nG, 256, 0, stream>>>(A, batch, nN, Wl, bl, out);
}